// Round 14
// baseline (362.620 us; speedup 1.0000x reference)
//
#include <hip/hip_runtime.h>
#include <cstdint>
#include <cstddef>

// ---------- types ----------
typedef __attribute__((ext_vector_type(8))) short short8;        // MFMA bf16 A/B frag (4 VGPR)
typedef __attribute__((ext_vector_type(4))) float f32x4;         // MFMA C/D frag
typedef __attribute__((ext_vector_type(4))) unsigned short ushort4_t;

// RNE float->bf16 (finite inputs only)
__device__ __forceinline__ unsigned short f2bf(float f) {
  unsigned u = __float_as_uint(f);
  u += 0x7FFFu + ((u >> 16) & 1u);
  return (unsigned short)(u >> 16);
}

// async global->LDS, 16B per lane. LDS dest is wave-uniform base (+lane*16 implicit).
__device__ __forceinline__ void gload_lds16(const void* g, const void* lds) {
  __builtin_amdgcn_global_load_lds((const __attribute__((address_space(1))) void*)g,
                                   (__attribute__((address_space(3))) void*)lds,
                                   16, 0, 0);
}

// Branch-free erf (A&S 7.1.26, abs err <= 1.5e-7), sign folded via bit ops.
__device__ __forceinline__ float erf_fast(float v) {
  float x = fabsf(v);
  float t = __builtin_amdgcn_rcpf(fmaf(0.3275911f, x, 1.0f));
  float p = fmaf(1.061405429f, t, -1.453152027f);
  p = fmaf(p, t, 1.421413741f);
  p = fmaf(p, t, -0.284496736f);
  p = fmaf(p, t, 0.254829592f);
  p = p * t;
  float e = fmaf(-p, __expf(-x * x), 1.0f);      // erf(|v|), >= 0
  unsigned s = __float_as_uint(v) & 0x80000000u;
  return __uint_as_float(__float_as_uint(e) | s);
}

// ---------- fused quantization kernel (r13, proven) ----------
__device__ __forceinline__ void statsq_row(const float* __restrict__ wr,
                                           unsigned short* __restrict__ wqr, int cols) {
  const int tid = threadIdx.x;
  const float4* w4 = (const float4*)wr;
  const int c4 = cols >> 2;
  float part = 0.f;
  for (int j = tid; j < c4; j += 256) {
    float4 v = w4[j];
    part += fabsf(v.x) + fabsf(v.y) + fabsf(v.z) + fabsf(v.w);
  }
#pragma unroll
  for (int o = 32; o > 0; o >>= 1) part += __shfl_down(part, o, 64);
  __shared__ float wsum[4];
  if ((tid & 63) == 0) wsum[tid >> 6] = part;
  __syncthreads();
  float mean = (wsum[0] + wsum[1] + wsum[2] + wsum[3]) / (float)cols;
  float s = 2.f * mean / sqrtf(127.f);
  ushort4_t* wq4 = (ushort4_t*)wqr;
  for (int j = tid; j < c4; j += 256) {
    float4 v = w4[j];
    float vv[4] = {v.x, v.y, v.z, v.w};
    ushort4_t o;
#pragma unroll
    for (int k = 0; k < 4; ++k) {
      float r = vv[k] / s;
      r = fminf(fmaxf(r, -128.f), 127.f);
      o[k] = f2bf(rintf(r) * s);
    }
    wq4[j] = o;
  }
}

__global__ void quant_fused_kernel(const float* __restrict__ w1, unsigned short* __restrict__ wq1, int C,
                                   const float* __restrict__ w2, unsigned short* __restrict__ wq2, int H,
                                   const float4* __restrict__ x, const float* __restrict__ s_a1,
                                   ushort4_t* __restrict__ xq, int n4, int c4mask) {
  const int NW1 = 4096, NW2 = 1024;
  const int bid = blockIdx.x;
  if (bid < NW1) { statsq_row(w1 + (size_t)bid * C, wq1 + (size_t)bid * C, C); return; }
  if (bid < NW1 + NW2) {
    const int row = bid - NW1;
    statsq_row(w2 + (size_t)row * H, wq2 + (size_t)row * H, H);
    return;
  }
  const int xb = bid - (NW1 + NW2);
  const int nxb = gridDim.x - (NW1 + NW2);
  const int stride = nxb * blockDim.x;
  for (int i = xb * blockDim.x + threadIdx.x; i < n4; i += stride) {
    float4 v = x[i];
    int c = (i & c4mask) << 2;
    float vv[4] = {v.x, v.y, v.z, v.w};
    ushort4_t o;
#pragma unroll
    for (int j = 0; j < 4; ++j) {
      float s = s_a1[c + j];
      float r = vv[j] / s;
      r = fminf(fmaxf(r, -128.f), 127.f);
      o[j] = f2bf(rintf(r) * s);
    }
    xq[i] = o;
  }
}

// ---------- high-occupancy 128x256 GEMM, BK=32, 3-ring LDS (A: MxK rm, B: NxK rm) ----------
// Mechanism change vs r11: 2 blocks/CU (72KB LDS + ~114 VGPR) -> 4 de-correlated
// waves/SIMD feed the LDS pipe through each other's stalls (m97 mechanism).
// Ring: tile t reads buf[t%3]; stage(t+3) -> buf[t%3] post-BAR (3 tiles deep).
// Per tile: p1: issue a1,b1(cur) [lgkm 4->8]; LGKM(4) [a0,b0 ready]; q00
//           p2: LGKM(2) [a1];                                        q10
//           p3: LGKM(0) [b1]; VMC(3) [stages(t+1) proven, counted];  BAR;
//               stage(t+3)->cur; read b0(next);                      q01
//           p4: read a0(next);                                       q11
// Proof chains: reads of buf-next come AFTER {per-wave VMC proof -> BAR} (block-
// wide). Stage->cur post-BAR after all cur reads drained per-wave (LGKM 4/2/0)
// pre-BAR. Tail: i2 ? VMC(3) : i1 ? VMC(0) : skip (r9-class fix by construction).
// Prologue: stage t0,t1,t2; VMC(6) [t0 proven]; BAR; read b0(0),a0(0).
#define BAR() { asm volatile("" ::: "memory"); __builtin_amdgcn_s_barrier(); asm volatile("" ::: "memory"); }
#define SB() __builtin_amdgcn_sched_barrier(0)
#define LGKM(n) { asm volatile("s_waitcnt lgkmcnt(" #n ")" ::: "memory"); SB(); }
#define VMC(n) { asm volatile("s_waitcnt vmcnt(" #n ")" ::: "memory"); SB(); }
#define PRIO1() __builtin_amdgcn_s_setprio(1)
#define PRIO0() __builtin_amdgcn_s_setprio(0)

#define RD(p) (*(const short8*)(p))

// stage one K-tile (kt) into ring offset OFF: A 8KB (1 gload/thr) + B 16KB (2)
#define STG3(kt, OFF) { \
  gload_lds16(Ags + (size_t)(kt) * 32, (const void*)(lds + (OFF) + w * 512)); \
  gload_lds16(Bgs0 + (size_t)(kt) * 32, (const void*)(lds + (OFF) + 4096 + w * 512)); \
  gload_lds16(Bgs1 + (size_t)(kt) * 32, (const void*)(lds + (OFF) + 8192 + w * 512)); }

// quadrant: 2x2 frags, one 16x16x32 MFMA each (K=32 = full BK)
#define MMQ4(aF, bF, mh, nh) { \
  _Pragma("unroll") for (int i_ = 0; i_ < 2; ++i_) \
  _Pragma("unroll") for (int j_ = 0; j_ < 2; ++j_) \
    acc[(mh) * 2 + i_][(nh) * 2 + j_] = __builtin_amdgcn_mfma_f32_16x16x32_bf16( \
        aF[i_], bF[j_], acc[(mh) * 2 + i_][(nh) * 2 + j_], 0, 0, 0); }

template <int EPI>
__global__ __launch_bounds__(512, 4) void gemm_bt_hp(
    const unsigned short* __restrict__ A, const unsigned short* __restrict__ B,
    const float* __restrict__ bias, const float* __restrict__ s2,
    const float* __restrict__ beta, unsigned short* __restrict__ Cq,
    float* __restrict__ Cf, int N, int K)
{
  __shared__ __align__(16) unsigned short lds[3 * 12288];   // 72 KB, 3-ring

  const int tid = threadIdx.x;
  const int w = tid >> 6, ll = tid & 63;
  const int wr = w >> 2, wc = w & 3;           // wave tile: 64 rows x 64 cols

  // T1: bijective XCD swizzle, y-major slab order (nwg % 8 == 0 for our grids)
  const int nwg = gridDim.x * gridDim.y;
  const int bid = blockIdx.x + gridDim.x * blockIdx.y;
  const int cpx = nwg >> 3;
  const int swz = (bid & 7) * cpx + (bid >> 3);
  const int gy = gridDim.y;
  const int bx = swz / gy, by = swz - bx * gy;
  const long bm = (long)bx * 128;
  const long bn = (long)by * 256;

  // staging sources, granule pre-swizzled: LDS[row][g] holds global granule
  // g ^ ((row>>1)&3)  (8 banks x 2-way on reads = free)
  const int ra = tid >> 2;
  const int ga = (tid & 3) ^ ((tid >> 3) & 3);
  const unsigned short* Ags  = A + ((size_t)bm + ra) * K + ga * 8;
  const unsigned short* Bgs0 = B + ((size_t)bn + ra) * K + ga * 8;
  const unsigned short* Bgs1 = B + ((size_t)bn + 128 + ra) * K + ga * 8;

  // per-lane ds_read bases (u16 elems); frag mi/ni offset = 512 each; ring += 12288
  const int llo = ll & 15, lhi = ll >> 4;
  const int gread = lhi ^ ((llo >> 1) & 3);
  const unsigned short* aP = lds + ((wr * 64 + llo) * 32 + gread * 8);
  const unsigned short* bP = lds + (4096 + (wc * 64 + llo) * 32 + gread * 8);

  f32x4 acc[4][4] = {};
  short8 a0[2], a1[2], b0[2], b1[2];

  const int nkt = K >> 5;   // 32 (GEMM1) / 128 (GEMM2)

  // ---- prologue: stage t0,t1,t2; prove t0; pre-read b0(0), a0(0) ----
  STG3(0, 0); STG3(1, 12288); STG3(2, 24576);
  VMC(6);                        // t0's 3 drained; t1,t2 (6) in flight
  BAR();
  b0[0] = RD(bP + 0);   b0[1] = RD(bP + 512);  SB();
  a0[0] = RD(aP + 0);   a0[1] = RD(aP + 512);  SB();   // lgkm outstanding = 4

  int curOff = 0, nxtOff = 12288;
  for (int t = 0; t < nkt; ++t) {
    const bool i1 = (t + 1 < nkt), i2 = (t + 2 < nkt), i3 = (t + 3 < nkt);

    // p1: issue a1,b1(cur); drain a0,b0; q00
    a1[0] = RD(aP + curOff + 1024); a1[1] = RD(aP + curOff + 1536); SB();
    b1[0] = RD(bP + curOff + 1024); b1[1] = RD(bP + curOff + 1536); SB();
    LGKM(4);
    PRIO1(); MMQ4(a0, b0, 0, 0); PRIO0();

    // p2: drain a1; q10
    LGKM(2);
    PRIO1(); MMQ4(a1, b0, 1, 0); PRIO0();

    // p3: drain b1; prove stages(t+1) (counted); BAR; stage t+3 -> cur; read b0(next); q01
    LGKM(0);
    if (i2)      { VMC(3); }
    else if (i1) { VMC(0); }
    BAR();
    if (i3) STG3(t + 3, curOff);
    if (i1) { b0[0] = RD(bP + nxtOff); b0[1] = RD(bP + nxtOff + 512); SB(); }
    PRIO1(); MMQ4(a0, b1, 0, 1); PRIO0();

    // p4: read a0(next); q11
    if (i1) { a0[0] = RD(aP + nxtOff); a0[1] = RD(aP + nxtOff + 512); SB(); }
    PRIO1(); MMQ4(a1, b1, 1, 1); PRIO0();

    curOff = nxtOff;
    nxtOff = (nxtOff == 24576) ? 0 : nxtOff + 12288;
  }

  // ---- epilogue; C/D layout: col = lane&15, row = (lane>>4)*4 + reg ----
  const int lr = lhi;
  const int lc = llo;
#pragma unroll
  for (int NI = 0; NI < 4; ++NI) {
    const long col = bn + wc * 64 + NI * 16 + lc;
    const float bv = bias[col];
    float sv = 1.f, bev = 0.f, inv = 1.f;
    if (EPI == 0) { sv = s2[col]; bev = beta[col]; inv = 1.0f / sv; }
#pragma unroll
    for (int MI = 0; MI < 4; ++MI) {
#pragma unroll
      for (int r = 0; r < 4; ++r) {
        const size_t rowg = (size_t)(bm + wr * 64 + MI * 16 + lr * 4 + r);
        float v = acc[MI][NI][r] + bv;
        if (EPI == 0) {
          float g = 0.5f * v * (1.f + erf_fast(v * 0.70710678118654752f));
          float rr = (g - bev) * inv;
          rr = fminf(fmaxf(rr, 0.f), 255.f);
          Cq[rowg * N + col] = f2bf(fmaf(rintf(rr), sv, bev));
        } else {
          Cf[rowg * N + col] = v;
        }
      }
    }
  }
}

// ---------- launch ----------
extern "C" void kernel_launch(void* const* d_in, const int* in_sizes, int n_in,
                              void* d_out, int out_size, void* d_ws, size_t ws_size,
                              hipStream_t stream) {
  const float* x     = (const float*)d_in[0];
  const float* w1    = (const float*)d_in[1];
  const float* b1    = (const float*)d_in[2];
  const float* w2    = (const float*)d_in[3];
  const float* b2    = (const float*)d_in[4];
  const float* s_a1  = (const float*)d_in[5];
  const float* s_a2  = (const float*)d_in[6];
  const float* beta2 = (const float*)d_in[7];
  float* out = (float*)d_out;

  const int C = 1024, H = 4096;
  const int M = in_sizes[0] / C;  // 16384

  // workspace layout (bf16 bit-patterns as u16): xq | wq1 | wq2 | hq
  unsigned short* xq  = (unsigned short*)d_ws;
  unsigned short* wq1 = xq  + (size_t)M * C;
  unsigned short* wq2 = wq1 + (size_t)H * C;
  unsigned short* hq  = wq2 + (size_t)C * H;

  quant_fused_kernel<<<4096 + 1024 + 2048, 256, 0, stream>>>(
      w1, wq1, C, w2, wq2, H,
      (const float4*)x, s_a1, (ushort4_t*)xq, M * C / 4, C / 4 - 1);

  dim3 g1(M / 128, H / 256);  // 128 x 16
  gemm_bt_hp<0><<<g1, 512, 0, stream>>>(xq, wq1, b1, s_a2, beta2, hq, nullptr, H, C);
  dim3 g2(M / 128, C / 256);  // 128 x 4
  gemm_bt_hp<1><<<g2, 512, 0, stream>>>(hq, wq2, b2, nullptr, nullptr, nullptr, out, C, H);
}